// Round 9
// baseline (656.209 us; speedup 1.0000x reference)
//
#include <hip/hip_runtime.h>
#include <hip/hip_bf16.h>
#include <math.h>

#define B 64
#define L 2048
#define C 1024          // D_K = D_Q
#define NH 8
#define DK 128
#define SCALE 0.08838834764831845f   // 1/sqrt(128)

// ---------------------------------------------------------------------------
// k_qs: qs[b, j] = bias[j] + sum_c q[b,c] * wq[j,c]   (64 x 1024)
__global__ void k_qs(const float* __restrict__ q, const float* __restrict__ wq,
                     const float* __restrict__ bq, float* __restrict__ qs) {
    int t = threadIdx.x, w = t >> 6, lane = t & 63;
    int j = blockIdx.x * 4 + w;
    float4 W[4];
#pragma unroll
    for (int kk = 0; kk < 4; kk++)
        W[kk] = *(const float4*)&wq[(size_t)j * C + kk * 256 + lane * 4];
    float bj = bq[j];
    for (int b = 0; b < B; b++) {
        float s = 0.f;
#pragma unroll
        for (int kk = 0; kk < 4; kk++) {
            float4 qv = *(const float4*)&q[(size_t)b * C + kk * 256 + lane * 4];
            s += W[kk].x * qv.x + W[kk].y * qv.y + W[kk].z * qv.z + W[kk].w * qv.w;
        }
#pragma unroll
        for (int off = 32; off; off >>= 1) s += __shfl_xor(s, off, 64);
        if (lane == 0) qs[(size_t)b * C + j] = s + bj;
    }
}

// ---------------------------------------------------------------------------
// k_qtilde: qtilde[b,n,c] = SCALE * sum_d qs[b, n*128+d] * wk[n*128+d, c]
__global__ void k_qtilde(const float* __restrict__ qs, const float* __restrict__ wk,
                         float* __restrict__ qtilde) {
    int n = blockIdx.x >> 2, cc = blockIdx.x & 3, bg = blockIdx.y;
    int t = threadIdx.x;
    int c = cc * 256 + t;
    __shared__ float qss[8][128];
    for (int p = 0; p < 4; p++) {
        int e = p * 256 + t;
        int i = e >> 7, d = e & 127;
        qss[i][d] = qs[(size_t)(bg * 8 + i) * C + n * DK + d];
    }
    __syncthreads();
    float acc[8];
#pragma unroll
    for (int i = 0; i < 8; i++) acc[i] = 0.f;
    for (int d = 0; d < DK; d++) {
        float wv = wk[(size_t)(n * DK + d) * C + c];
#pragma unroll
        for (int i = 0; i < 8; i++) acc[i] += qss[i][d] * wv;
    }
#pragma unroll
    for (int i = 0; i < 8; i++)
        qtilde[((size_t)(bg * 8 + i) * NH + n) * C + c] = acc[i] * SCALE;
}

// ---------------------------------------------------------------------------
// k_fused6: one streaming pass over k. TLP-based latency hiding:
// 2 heads/wave -> ~110 VGPR -> 4 waves/SIMD (2 blocks/CU) via launch_bounds.
// Grid (64 b, 8 lp of 256 rows). 512 thr = 8 waves: hp = w&3 (heads hp*2..+1),
// rh = w>>2 (128-row half). Lane owns c-slots {kk*256+lane*4}. Single kv
// buffer, no prefetch. Barrier per 4 rows keeps head-waves' k-window in L2.
__global__ __launch_bounds__(512, 4) void k_fused6(
    const float* __restrict__ kmat, const float* __restrict__ qtilde,
    const unsigned char* __restrict__ mask,
    float* __restrict__ pout,             // (n*B + b)*L + l : exp(score)
    float* __restrict__ accpart,          // [b][lp8][n][C]
    float* __restrict__ zpart) {          // [b][lp8][n]
    const int b = blockIdx.x, lp = blockIdx.y;
    const int t = threadIdx.x, w = t >> 6, lane = t & 63;
    const int hp = w & 3;                // head pair -> heads hp*2, hp*2+1
    const int rh = w >> 2;               // row half (128 rows)
    const int lbase = lp * 256 + rh * 128;

    __shared__ float ctxl[NH * C];       // 32 KB
    __shared__ float zl[NH];

    float4 qt[2][4];
#pragma unroll
    for (int j = 0; j < 2; j++)
#pragma unroll
        for (int kk = 0; kk < 4; kk++)
            qt[j][kk] = *(const float4*)&qtilde[((size_t)b * NH + hp * 2 + j) * C + kk * 256 + lane * 4];

    float4 acc[2][4];
#pragma unroll
    for (int j = 0; j < 2; j++)
#pragma unroll
        for (int kk = 0; kk < 4; kk++) acc[j][kk] = make_float4(0.f, 0.f, 0.f, 0.f);
    float zacc = 0.f;

    const float* kp = kmat + ((size_t)b * L + lbase) * C + lane * 4;
    const unsigned char* mp = mask + (size_t)b * L + lbase;

    for (int rb = 0; rb < 32; rb++) {
        uchar4 mb = *(const uchar4*)&mp[rb * 4];
        float ss[4];
#pragma unroll
        for (int rr = 0; rr < 4; rr++) {
            const float* rp = kp + (size_t)(rb * 4 + rr) * C;
            float4 kv0 = *(const float4*)(rp);
            float4 kv1 = *(const float4*)(rp + 256);
            float4 kv2 = *(const float4*)(rp + 512);
            float4 kv3 = *(const float4*)(rp + 768);
            float s0 = qt[0][0].x * kv0.x + qt[0][0].y * kv0.y + qt[0][0].z * kv0.z + qt[0][0].w * kv0.w
                     + qt[0][1].x * kv1.x + qt[0][1].y * kv1.y + qt[0][1].z * kv1.z + qt[0][1].w * kv1.w
                     + qt[0][2].x * kv2.x + qt[0][2].y * kv2.y + qt[0][2].z * kv2.z + qt[0][2].w * kv2.w
                     + qt[0][3].x * kv3.x + qt[0][3].y * kv3.y + qt[0][3].z * kv3.z + qt[0][3].w * kv3.w;
            float s1 = qt[1][0].x * kv0.x + qt[1][0].y * kv0.y + qt[1][0].z * kv0.z + qt[1][0].w * kv0.w
                     + qt[1][1].x * kv1.x + qt[1][1].y * kv1.y + qt[1][1].z * kv1.z + qt[1][1].w * kv1.w
                     + qt[1][2].x * kv2.x + qt[1][2].y * kv2.y + qt[1][2].z * kv2.z + qt[1][2].w * kv2.w
                     + qt[1][3].x * kv3.x + qt[1][3].y * kv3.y + qt[1][3].z * kv3.z + qt[1][3].w * kv3.w;
            // butterfly: lane ends with FULL score of head hp*2 + (lane&1)
            float keep = (lane & 1) ? s1 : s0;
            float give = (lane & 1) ? s0 : s1;
            float v = keep + __shfl_xor(give, 1, 64);
            v += __shfl_xor(v, 2, 64);
            v += __shfl_xor(v, 4, 64);
            v += __shfl_xor(v, 8, 64);
            v += __shfl_xor(v, 16, 64);
            v += __shfl_xor(v, 32, 64);
            unsigned char mk = (rr == 0) ? mb.x : (rr == 1) ? mb.y : (rr == 2) ? mb.z : mb.w;
            float p = __expf(mk ? -INFINITY : v);
            zacc += p;      // p is the FULL row sum for head (lane&1):
            ss[rr] = p;     // zacc = complete partial Z, no cross-lane reduce.
            float p1 = __shfl_xor(p, 1, 64);   // p of the other head
            acc[0][0].x += p  * kv0.x; acc[0][0].y += p  * kv0.y; acc[0][0].z += p  * kv0.z; acc[0][0].w += p  * kv0.w;
            acc[0][1].x += p  * kv1.x; acc[0][1].y += p  * kv1.y; acc[0][1].z += p  * kv1.z; acc[0][1].w += p  * kv1.w;
            acc[0][2].x += p  * kv2.x; acc[0][2].y += p  * kv2.y; acc[0][2].z += p  * kv2.z; acc[0][2].w += p  * kv2.w;
            acc[0][3].x += p  * kv3.x; acc[0][3].y += p  * kv3.y; acc[0][3].z += p  * kv3.z; acc[0][3].w += p  * kv3.w;
            acc[1][0].x += p1 * kv0.x; acc[1][0].y += p1 * kv0.y; acc[1][0].z += p1 * kv0.z; acc[1][0].w += p1 * kv0.w;
            acc[1][1].x += p1 * kv1.x; acc[1][1].y += p1 * kv1.y; acc[1][1].z += p1 * kv1.z; acc[1][1].w += p1 * kv1.w;
            acc[1][2].x += p1 * kv2.x; acc[1][2].y += p1 * kv2.y; acc[1][2].z += p1 * kv2.z; acc[1][2].w += p1 * kv2.w;
            acc[1][3].x += p1 * kv3.x; acc[1][3].y += p1 * kv3.y; acc[1][3].z += p1 * kv3.z; acc[1][3].w += p1 * kv3.w;
        }
        if (lane < 2) {
            float4 o = make_float4(ss[0], ss[1], ss[2], ss[3]);
            *(float4*)&pout[((size_t)(hp * 2 + lane) * B + b) * L + lbase + rb * 4] = o;
        }
        __syncthreads();   // lockstep across head-waves -> shared rows stay in L2
    }

    // phased LDS merge across rh; un-permute head h = hp*2 + ((lane&1)^j)
    for (int ph = 0; ph < 2; ph++) {
        if (rh == ph) {
#pragma unroll
            for (int j = 0; j < 2; j++) {
                int h = hp * 2 + ((lane & 1) ^ j);
                float* dst = &ctxl[(size_t)h * C + lane * 4];
                if (ph == 0) {
#pragma unroll
                    for (int kk = 0; kk < 4; kk++)
                        *(float4*)&dst[kk * 256] = acc[j][kk];
                } else {
#pragma unroll
                    for (int kk = 0; kk < 4; kk++) {
                        float4 o = *(const float4*)&dst[kk * 256];
                        float4 a = acc[j][kk];
                        o.x += a.x; o.y += a.y; o.z += a.z; o.w += a.w;
                        *(float4*)&dst[kk * 256] = o;
                    }
                }
            }
            if (lane < 2) {
                if (ph == 0) zl[hp * 2 + lane] = zacc;
                else         zl[hp * 2 + lane] += zacc;
            }
        }
        __syncthreads();
    }
    float* ap = accpart + ((size_t)b * 8 + lp) * (NH * C);
#pragma unroll
    for (int i = 0; i < 4; i++) {
        int idx = t * 16 + i * 4;
        *(float4*)&ap[idx] = *(const float4*)&ctxl[idx];
    }
    if (t < NH) zpart[((size_t)b * 8 + lp) * NH + t] = zl[t];
}

// ---------------------------------------------------------------------------
// k_epilogue: per b — (A) Z reduce, (B) ctx = sum_lp accpart * zi -> LDS,
// (C) out[b,j] = bv[j] + wv[j,:]·ctx[n(j),:], (D) scale pout rows by zi.
__global__ __launch_bounds__(1024) void k_epilogue(
    const float* __restrict__ accpart, const float* __restrict__ zpart,
    const float* __restrict__ wvw, const float* __restrict__ bv,
    float* __restrict__ pout, float* __restrict__ out) {
    const int b = blockIdx.x;
    const int t = threadIdx.x;
    __shared__ float ctxl[NH * C];
    __shared__ float zi[NH];
    if (t < NH) {
        float z = 0.f;
#pragma unroll
        for (int lp = 0; lp < 8; lp++) z += zpart[((size_t)b * 8 + lp) * NH + t];
        zi[t] = 1.0f / z;
    }
    __syncthreads();
    // (B) ctx reduce into LDS
#pragma unroll
    for (int i = 0; i < 2; i++) {
        int f4 = i * 1024 + t;               // 0..2047 float4 index into [NH*C]
        float4 s = make_float4(0.f, 0.f, 0.f, 0.f);
#pragma unroll
        for (int lp = 0; lp < 8; lp++) {
            float4 a = *(const float4*)&accpart[((size_t)b * 8 + lp) * (NH * C) + f4 * 4];
            s.x += a.x; s.y += a.y; s.z += a.z; s.w += a.w;
        }
        float sc = zi[f4 >> 8];
        s.x *= sc; s.y *= sc; s.z *= sc; s.w *= sc;
        *(float4*)&ctxl[f4 * 4] = s;
    }
    __syncthreads();
    // (C) output projection: wave per 64 j's
    {
        int wv_i = t >> 6, lane = t & 63;
        for (int jj = 0; jj < 64; jj++) {
            int j = wv_i * 64 + jj;
            int n = j >> 7;
            float s = 0.f;
#pragma unroll
            for (int kk = 0; kk < 4; kk++) {
                float4 W = *(const float4*)&wvw[(size_t)j * C + kk * 256 + lane * 4];
                float4 cv = *(const float4*)&ctxl[(size_t)n * C + kk * 256 + lane * 4];
                s += W.x * cv.x + W.y * cv.y + W.z * cv.z + W.w * cv.w;
            }
#pragma unroll
            for (int off = 32; off; off >>= 1) s += __shfl_xor(s, off, 64);
            if (lane == 0) out[(size_t)b * (NH * DK) + j] = s + bv[j];
        }
    }
    // (D) pout scale (rows (n,b), all l)
    float4* p4 = (float4*)pout;
#pragma unroll
    for (int i = 0; i < 4; i++) {
        int e = i * 1024 + t;                // 0..4095 = 8 rows x 512 float4
        int n = e >> 9, off = e & 511;
        size_t idx = ((size_t)n * B + b) * (L / 4) + off;
        float4 v = p4[idx];
        float sc = zi[n];
        v.x *= sc; v.y *= sc; v.z *= sc; v.w *= sc;
        p4[idx] = v;
    }
}

// ---------------------------------------------------------------------------
extern "C" void kernel_launch(void* const* d_in, const int* in_sizes, int n_in,
                              void* d_out, int out_size, void* d_ws, size_t ws_size,
                              hipStream_t stream) {
    const float* q    = (const float*)d_in[0];
    const float* kmat = (const float*)d_in[1];
    const unsigned char* mask = (const unsigned char*)d_in[2];
    const float* wq = (const float*)d_in[3];
    const float* bq = (const float*)d_in[4];
    const float* wk = (const float*)d_in[5];
    // d_in[6] = w_ks_b: softmax-invariant -> unused.
    const float* wv = (const float*)d_in[7];
    const float* bv = (const float*)d_in[8];

    float* out  = (float*)d_out;            // (64, 1024)
    float* attn = out + B * NH * DK;        // (8*64, 2048): exp(s) -> scaled

    float* ws      = (float*)d_ws;
    float* qs      = ws;                     // 65536 floats (dead after k_qtilde)
    float* zpart   = ws;                     // 4096 floats overlay (64*8*8)
    float* qtilde  = ws + 65536;             // 524288 floats
    float* accpart = ws + 65536 + 524288;    // 64*8*8*1024 = 4194304 floats

    hipLaunchKernelGGL(k_qs, dim3(256), dim3(256), 0, stream, q, wq, bq, qs);
    hipLaunchKernelGGL(k_qtilde, dim3(32, 8), dim3(256), 0, stream, qs, wk, qtilde);
    hipLaunchKernelGGL(k_fused6, dim3(64, 8), dim3(512), 0, stream,
                       kmat, qtilde, mask, attn, accpart, zpart);
    hipLaunchKernelGGL(k_epilogue, dim3(64), dim3(1024), 0, stream,
                       accpart, zpart, wv, bv, attn, out);
}

// Round 10
// 309.038 us; speedup vs baseline: 2.1234x; 2.1234x over previous
//
#include <hip/hip_runtime.h>
#include <hip/hip_bf16.h>
#include <math.h>

#define B 64
#define L 2048
#define C 1024          // D_K = D_Q
#define NH 8
#define DK 128
#define SCALE 0.08838834764831845f   // 1/sqrt(128)

// ---------------------------------------------------------------------------
// k_qs: qs[b, j] = bias[j] + sum_c q[b,c] * wq[j,c]   (64 x 1024)
__global__ void k_qs(const float* __restrict__ q, const float* __restrict__ wq,
                     const float* __restrict__ bq, float* __restrict__ qs) {
    int t = threadIdx.x, w = t >> 6, lane = t & 63;
    int j = blockIdx.x * 4 + w;
    float4 W[4];
#pragma unroll
    for (int kk = 0; kk < 4; kk++)
        W[kk] = *(const float4*)&wq[(size_t)j * C + kk * 256 + lane * 4];
    float bj = bq[j];
    for (int b = 0; b < B; b++) {
        float s = 0.f;
#pragma unroll
        for (int kk = 0; kk < 4; kk++) {
            float4 qv = *(const float4*)&q[(size_t)b * C + kk * 256 + lane * 4];
            s += W[kk].x * qv.x + W[kk].y * qv.y + W[kk].z * qv.z + W[kk].w * qv.w;
        }
#pragma unroll
        for (int off = 32; off; off >>= 1) s += __shfl_xor(s, off, 64);
        if (lane == 0) qs[(size_t)b * C + j] = s + bj;
    }
}

// ---------------------------------------------------------------------------
// k_qtilde: qtilde[b,n,c] = SCALE * sum_d qs[b, n*128+d] * wk[n*128+d, c]
__global__ void k_qtilde(const float* __restrict__ qs, const float* __restrict__ wk,
                         float* __restrict__ qtilde) {
    int n = blockIdx.x >> 2, cc = blockIdx.x & 3, bg = blockIdx.y;
    int t = threadIdx.x;
    int c = cc * 256 + t;
    __shared__ float qss[8][128];
    for (int p = 0; p < 4; p++) {
        int e = p * 256 + t;
        int i = e >> 7, d = e & 127;
        qss[i][d] = qs[(size_t)(bg * 8 + i) * C + n * DK + d];
    }
    __syncthreads();
    float acc[8];
#pragma unroll
    for (int i = 0; i < 8; i++) acc[i] = 0.f;
    for (int d = 0; d < DK; d++) {
        float wv = wk[(size_t)(n * DK + d) * C + c];
#pragma unroll
        for (int i = 0; i < 8; i++) acc[i] += qss[i][d] * wv;
    }
#pragma unroll
    for (int i = 0; i < 8; i++)
        qtilde[((size_t)(bg * 8 + i) * NH + n) * C + c] = acc[i] * SCALE;
}

// ---------------------------------------------------------------------------
// k_fused7: one streaming pass over k. TLP latency hiding WITHOUT forced
// occupancy: launch_bounds(512,2) (the only spill-free contract measured);
// 2 heads/wave keeps natural VGPR ~110 -> 4 waves/SIMD by allocation.
// No barriers in the main loop (L2 absorbs the 4x hp-wave row reuse).
// Grid (64 b, 8 lp of 256 rows). 512 thr = 8 waves: hp = w&3, rh = w>>2.
__global__ __launch_bounds__(512, 2) void k_fused7(
    const float* __restrict__ kmat, const float* __restrict__ qtilde,
    const unsigned char* __restrict__ mask,
    float* __restrict__ pout,             // (n*B + b)*L + l : exp(score)
    float* __restrict__ accpart,          // [b][lp8][n][C]
    float* __restrict__ zpart) {          // [b][lp8][n]
    const int b = blockIdx.x, lp = blockIdx.y;
    const int t = threadIdx.x, w = t >> 6, lane = t & 63;
    const int hp = w & 3;                // head pair -> heads hp*2, hp*2+1
    const int rh = w >> 2;               // row half (128 rows)
    const int lbase = lp * 256 + rh * 128;

    __shared__ float ctxl[NH * C];       // 32 KB
    __shared__ float zl[NH];

    float4 qt[2][4];
#pragma unroll
    for (int j = 0; j < 2; j++)
#pragma unroll
        for (int kk = 0; kk < 4; kk++)
            qt[j][kk] = *(const float4*)&qtilde[((size_t)b * NH + hp * 2 + j) * C + kk * 256 + lane * 4];

    float4 acc[2][4];
#pragma unroll
    for (int j = 0; j < 2; j++)
#pragma unroll
        for (int kk = 0; kk < 4; kk++) acc[j][kk] = make_float4(0.f, 0.f, 0.f, 0.f);
    float zacc = 0.f;

    const float* kp = kmat + ((size_t)b * L + lbase) * C + lane * 4;
    const unsigned char* mp = mask + (size_t)b * L + lbase;

    for (int rb = 0; rb < 32; rb++) {
        uchar4 mb = *(const uchar4*)&mp[rb * 4];
        float ss[4];
#pragma unroll
        for (int rr = 0; rr < 4; rr++) {
            const float* rp = kp + (size_t)(rb * 4 + rr) * C;
            float4 kv0 = *(const float4*)(rp);
            float4 kv1 = *(const float4*)(rp + 256);
            float4 kv2 = *(const float4*)(rp + 512);
            float4 kv3 = *(const float4*)(rp + 768);
            float s0 = qt[0][0].x * kv0.x + qt[0][0].y * kv0.y + qt[0][0].z * kv0.z + qt[0][0].w * kv0.w
                     + qt[0][1].x * kv1.x + qt[0][1].y * kv1.y + qt[0][1].z * kv1.z + qt[0][1].w * kv1.w
                     + qt[0][2].x * kv2.x + qt[0][2].y * kv2.y + qt[0][2].z * kv2.z + qt[0][2].w * kv2.w
                     + qt[0][3].x * kv3.x + qt[0][3].y * kv3.y + qt[0][3].z * kv3.z + qt[0][3].w * kv3.w;
            float s1 = qt[1][0].x * kv0.x + qt[1][0].y * kv0.y + qt[1][0].z * kv0.z + qt[1][0].w * kv0.w
                     + qt[1][1].x * kv1.x + qt[1][1].y * kv1.y + qt[1][1].z * kv1.z + qt[1][1].w * kv1.w
                     + qt[1][2].x * kv2.x + qt[1][2].y * kv2.y + qt[1][2].z * kv2.z + qt[1][2].w * kv2.w
                     + qt[1][3].x * kv3.x + qt[1][3].y * kv3.y + qt[1][3].z * kv3.z + qt[1][3].w * kv3.w;
            // butterfly: lane ends with FULL score of head hp*2 + (lane&1)
            float keep = (lane & 1) ? s1 : s0;
            float give = (lane & 1) ? s0 : s1;
            float v = keep + __shfl_xor(give, 1, 64);
            v += __shfl_xor(v, 2, 64);
            v += __shfl_xor(v, 4, 64);
            v += __shfl_xor(v, 8, 64);
            v += __shfl_xor(v, 16, 64);
            v += __shfl_xor(v, 32, 64);
            unsigned char mk = (rr == 0) ? mb.x : (rr == 1) ? mb.y : (rr == 2) ? mb.z : mb.w;
            float p = __expf(mk ? -INFINITY : v);
            zacc += p;      // p is the FULL row sum for head (lane&1):
            ss[rr] = p;     // zacc = complete partial Z, no cross-lane reduce.
            float p1 = __shfl_xor(p, 1, 64);   // p of the other head
            acc[0][0].x += p  * kv0.x; acc[0][0].y += p  * kv0.y; acc[0][0].z += p  * kv0.z; acc[0][0].w += p  * kv0.w;
            acc[0][1].x += p  * kv1.x; acc[0][1].y += p  * kv1.y; acc[0][1].z += p  * kv1.z; acc[0][1].w += p  * kv1.w;
            acc[0][2].x += p  * kv2.x; acc[0][2].y += p  * kv2.y; acc[0][2].z += p  * kv2.z; acc[0][2].w += p  * kv2.w;
            acc[0][3].x += p  * kv3.x; acc[0][3].y += p  * kv3.y; acc[0][3].z += p  * kv3.z; acc[0][3].w += p  * kv3.w;
            acc[1][0].x += p1 * kv0.x; acc[1][0].y += p1 * kv0.y; acc[1][0].z += p1 * kv0.z; acc[1][0].w += p1 * kv0.w;
            acc[1][1].x += p1 * kv1.x; acc[1][1].y += p1 * kv1.y; acc[1][1].z += p1 * kv1.z; acc[1][1].w += p1 * kv1.w;
            acc[1][2].x += p1 * kv2.x; acc[1][2].y += p1 * kv2.y; acc[1][2].z += p1 * kv2.z; acc[1][2].w += p1 * kv2.w;
            acc[1][3].x += p1 * kv3.x; acc[1][3].y += p1 * kv3.y; acc[1][3].z += p1 * kv3.z; acc[1][3].w += p1 * kv3.w;
        }
        if (lane < 2) {
            float4 o = make_float4(ss[0], ss[1], ss[2], ss[3]);
            *(float4*)&pout[((size_t)(hp * 2 + lane) * B + b) * L + lbase + rb * 4] = o;
        }
    }

    // phased LDS merge across rh; un-permute head h = hp*2 + ((lane&1)^j).
    // (ctxl/zl first written here, so no pre-barrier needed.)
    for (int ph = 0; ph < 2; ph++) {
        if (rh == ph) {
#pragma unroll
            for (int j = 0; j < 2; j++) {
                int h = hp * 2 + ((lane & 1) ^ j);
                float* dst = &ctxl[(size_t)h * C + lane * 4];
                if (ph == 0) {
#pragma unroll
                    for (int kk = 0; kk < 4; kk++)
                        *(float4*)&dst[kk * 256] = acc[j][kk];
                } else {
#pragma unroll
                    for (int kk = 0; kk < 4; kk++) {
                        float4 o = *(const float4*)&dst[kk * 256];
                        float4 a = acc[j][kk];
                        o.x += a.x; o.y += a.y; o.z += a.z; o.w += a.w;
                        *(float4*)&dst[kk * 256] = o;
                    }
                }
            }
            if (lane < 2) {
                if (ph == 0) zl[hp * 2 + lane] = zacc;
                else         zl[hp * 2 + lane] += zacc;
            }
        }
        __syncthreads();
    }
    float* ap = accpart + ((size_t)b * 8 + lp) * (NH * C);
#pragma unroll
    for (int i = 0; i < 4; i++) {
        int idx = t * 16 + i * 4;
        *(float4*)&ap[idx] = *(const float4*)&ctxl[idx];
    }
    if (t < NH) zpart[((size_t)b * 8 + lp) * NH + t] = zl[t];
}

// ---------------------------------------------------------------------------
// k_epilogue: per b — (A) Z reduce, (B) ctx = sum_lp accpart * zi -> LDS,
// (C) out[b,j] = bv[j] + wv[j,:]·ctx[n(j),:], (D) scale pout rows by zi.
__global__ __launch_bounds__(1024) void k_epilogue(
    const float* __restrict__ accpart, const float* __restrict__ zpart,
    const float* __restrict__ wvw, const float* __restrict__ bv,
    float* __restrict__ pout, float* __restrict__ out) {
    const int b = blockIdx.x;
    const int t = threadIdx.x;
    __shared__ float ctxl[NH * C];
    __shared__ float zi[NH];
    if (t < NH) {
        float z = 0.f;
#pragma unroll
        for (int lp = 0; lp < 8; lp++) z += zpart[((size_t)b * 8 + lp) * NH + t];
        zi[t] = 1.0f / z;
    }
    __syncthreads();
    // (B) ctx reduce into LDS
#pragma unroll
    for (int i = 0; i < 2; i++) {
        int f4 = i * 1024 + t;               // 0..2047 float4 index into [NH*C]
        float4 s = make_float4(0.f, 0.f, 0.f, 0.f);
#pragma unroll
        for (int lp = 0; lp < 8; lp++) {
            float4 a = *(const float4*)&accpart[((size_t)b * 8 + lp) * (NH * C) + f4 * 4];
            s.x += a.x; s.y += a.y; s.z += a.z; s.w += a.w;
        }
        float sc = zi[f4 >> 8];
        s.x *= sc; s.y *= sc; s.z *= sc; s.w *= sc;
        *(float4*)&ctxl[f4 * 4] = s;
    }
    __syncthreads();
    // (C) output projection: wave per 64 j's
    {
        int wv_i = t >> 6, lane = t & 63;
        for (int jj = 0; jj < 64; jj++) {
            int j = wv_i * 64 + jj;
            int n = j >> 7;
            float s = 0.f;
#pragma unroll
            for (int kk = 0; kk < 4; kk++) {
                float4 W = *(const float4*)&wvw[(size_t)j * C + kk * 256 + lane * 4];
                float4 cv = *(const float4*)&ctxl[(size_t)n * C + kk * 256 + lane * 4];
                s += W.x * cv.x + W.y * cv.y + W.z * cv.z + W.w * cv.w;
            }
#pragma unroll
            for (int off = 32; off; off >>= 1) s += __shfl_xor(s, off, 64);
            if (lane == 0) out[(size_t)b * (NH * DK) + j] = s + bv[j];
        }
    }
    // (D) pout scale (rows (n,b), all l)
    float4* p4 = (float4*)pout;
#pragma unroll
    for (int i = 0; i < 4; i++) {
        int e = i * 1024 + t;                // 0..4095 = 8 rows x 512 float4
        int n = e >> 9, off = e & 511;
        size_t idx = ((size_t)n * B + b) * (L / 4) + off;
        float4 v = p4[idx];
        float sc = zi[n];
        v.x *= sc; v.y *= sc; v.z *= sc; v.w *= sc;
        p4[idx] = v;
    }
}

// ---------------------------------------------------------------------------
extern "C" void kernel_launch(void* const* d_in, const int* in_sizes, int n_in,
                              void* d_out, int out_size, void* d_ws, size_t ws_size,
                              hipStream_t stream) {
    const float* q    = (const float*)d_in[0];
    const float* kmat = (const float*)d_in[1];
    const unsigned char* mask = (const unsigned char*)d_in[2];
    const float* wq = (const float*)d_in[3];
    const float* bq = (const float*)d_in[4];
    const float* wk = (const float*)d_in[5];
    // d_in[6] = w_ks_b: softmax-invariant -> unused.
    const float* wv = (const float*)d_in[7];
    const float* bv = (const float*)d_in[8];

    float* out  = (float*)d_out;            // (64, 1024)
    float* attn = out + B * NH * DK;        // (8*64, 2048): exp(s) -> scaled

    float* ws      = (float*)d_ws;
    float* qs      = ws;                     // 65536 floats (dead after k_qtilde)
    float* zpart   = ws;                     // 4096 floats overlay (64*8*8)
    float* qtilde  = ws + 65536;             // 524288 floats
    float* accpart = ws + 65536 + 524288;    // 64*8*8*1024 = 4194304 floats

    hipLaunchKernelGGL(k_qs, dim3(256), dim3(256), 0, stream, q, wq, bq, qs);
    hipLaunchKernelGGL(k_qtilde, dim3(32, 8), dim3(256), 0, stream, qs, wk, qtilde);
    hipLaunchKernelGGL(k_fused7, dim3(64, 8), dim3(512), 0, stream,
                       kmat, qtilde, mask, attn, accpart, zpart);
    hipLaunchKernelGGL(k_epilogue, dim3(64), dim3(1024), 0, stream,
                       accpart, zpart, wv, bv, attn, out);
}

// Round 11
// 270.553 us; speedup vs baseline: 2.4254x; 1.1422x over previous
//
#include <hip/hip_runtime.h>
#include <hip/hip_bf16.h>
#include <math.h>

#define B 64
#define L 2048
#define C 1024          // D_K = D_Q
#define NH 8
#define DK 128
#define SCALE 0.08838834764831845f   // 1/sqrt(128)

// ---------------------------------------------------------------------------
// k_qs: qs[b, j] = bias[j] + sum_c q[b,c] * wq[j,c]   (64 x 1024)
__global__ void k_qs(const float* __restrict__ q, const float* __restrict__ wq,
                     const float* __restrict__ bq, float* __restrict__ qs) {
    int t = threadIdx.x, w = t >> 6, lane = t & 63;
    int j = blockIdx.x * 4 + w;
    float4 W[4];
#pragma unroll
    for (int kk = 0; kk < 4; kk++)
        W[kk] = *(const float4*)&wq[(size_t)j * C + kk * 256 + lane * 4];
    float bj = bq[j];
    for (int b = 0; b < B; b++) {
        float s = 0.f;
#pragma unroll
        for (int kk = 0; kk < 4; kk++) {
            float4 qv = *(const float4*)&q[(size_t)b * C + kk * 256 + lane * 4];
            s += W[kk].x * qv.x + W[kk].y * qv.y + W[kk].z * qv.z + W[kk].w * qv.w;
        }
#pragma unroll
        for (int off = 32; off; off >>= 1) s += __shfl_xor(s, off, 64);
        if (lane == 0) qs[(size_t)b * C + j] = s + bj;
    }
}

// ---------------------------------------------------------------------------
// k_qtilde: qtilde[b,n,c] = SCALE * sum_d qs[b, n*128+d] * wk[n*128+d, c]
__global__ void k_qtilde(const float* __restrict__ qs, const float* __restrict__ wk,
                         float* __restrict__ qtilde) {
    int n = blockIdx.x >> 2, cc = blockIdx.x & 3, bg = blockIdx.y;
    int t = threadIdx.x;
    int c = cc * 256 + t;
    __shared__ float qss[8][128];
    for (int p = 0; p < 4; p++) {
        int e = p * 256 + t;
        int i = e >> 7, d = e & 127;
        qss[i][d] = qs[(size_t)(bg * 8 + i) * C + n * DK + d];
    }
    __syncthreads();
    float acc[8];
#pragma unroll
    for (int i = 0; i < 8; i++) acc[i] = 0.f;
    for (int d = 0; d < DK; d++) {
        float wv = wk[(size_t)(n * DK + d) * C + c];
#pragma unroll
        for (int i = 0; i < 8; i++) acc[i] += qss[i][d] * wv;
    }
#pragma unroll
    for (int i = 0; i < 8; i++)
        qtilde[((size_t)(bg * 8 + i) * NH + n) * C + c] = acc[i] * SCALE;
}

// ---------------------------------------------------------------------------
// k_fused3 (round-5 verified, best-measured structure): one streaming pass
// over k. 512 thr = 8 waves = 4 chunks x 2 hg. Wave: 4 heads x 128 rows.
// Lane owns c-slots {kk*256+lane*4}. Direct exp (softmax shift-invariance;
// f32 safe) -> partials add plainly. Dist-1 register prefetch, no barriers
// in the main loop. launch_bounds(512,2): the only spill-free contract.
__global__ __launch_bounds__(512, 2) void k_fused3(
    const float* __restrict__ kmat, const float* __restrict__ qtilde,
    const unsigned char* __restrict__ mask,
    float* __restrict__ pout,             // (n*B + b)*L + l : exp(score)
    float* __restrict__ accpart,          // [b][lp4][n][C]
    float* __restrict__ zpart) {          // [b][lp4][n]
    const int b = blockIdx.x, lp = blockIdx.y;
    const int t = threadIdx.x, w = t >> 6, lane = t & 63;
    const int chunk = w >> 1;            // 0..3 (128 rows each)
    const int hg = w & 1;                // 0..1 (heads hg*4..hg*4+3)
    const int l0 = lp * 512 + chunk * 128;
    const int hl = lane & 3;

    __shared__ float ctxl[NH * C];       // 32 KB
    __shared__ float zl[NH];

    float4 qt[4][4];
#pragma unroll
    for (int j = 0; j < 4; j++)
#pragma unroll
        for (int kk = 0; kk < 4; kk++)
            qt[j][kk] = *(const float4*)&qtilde[((size_t)b * NH + hg * 4 + j) * C + kk * 256 + lane * 4];

    float4 acc[4][4];
#pragma unroll
    for (int j = 0; j < 4; j++)
#pragma unroll
        for (int kk = 0; kk < 4; kk++) acc[j][kk] = make_float4(0.f, 0.f, 0.f, 0.f);
    float zacc = 0.f;

    const float* kp = kmat + ((size_t)b * L + l0) * C + lane * 4;
    const unsigned char* mp = mask + (size_t)b * L + l0;

    float4 kv[2][4];
#pragma unroll
    for (int kk = 0; kk < 4; kk++) kv[0][kk] = *(const float4*)(kp + kk * 256);

    for (int rb = 0; rb < 32; rb++) {
        uchar4 mb = *(const uchar4*)&mp[rb * 4];
        float ss[4];
#pragma unroll
        for (int rr = 0; rr < 4; rr++) {
            const int r = rb * 4 + rr;
            const int cur = r & 1;
            if (r < 127) {
                const float* np = kp + (size_t)(r + 1) * C;
#pragma unroll
                for (int kk = 0; kk < 4; kk++)
                    kv[cur ^ 1][kk] = *(const float4*)(np + kk * 256);
            }
            float s0 = 0.f, s1 = 0.f, s2 = 0.f, s3 = 0.f;
#pragma unroll
            for (int kk = 0; kk < 4; kk++) {
                float4 kq = kv[cur][kk];
                s0 += qt[0][kk].x * kq.x + qt[0][kk].y * kq.y + qt[0][kk].z * kq.z + qt[0][kk].w * kq.w;
                s1 += qt[1][kk].x * kq.x + qt[1][kk].y * kq.y + qt[1][kk].z * kq.z + qt[1][kk].w * kq.w;
                s2 += qt[2][kk].x * kq.x + qt[2][kk].y * kq.y + qt[2][kk].z * kq.z + qt[2][kk].w * kq.w;
                s3 += qt[3][kk].x * kq.x + qt[3][kk].y * kq.y + qt[3][kk].z * kq.z + qt[3][kk].w * kq.w;
            }
            // butterfly: lane ends with full score of head (lane&3)
            float a01 = (lane & 1) ? s1 : s0;
            float g01 = (lane & 1) ? s0 : s1;
            float a23 = (lane & 1) ? s3 : s2;
            float g23 = (lane & 1) ? s2 : s3;
            float u  = a01 + __shfl_xor(g01, 1, 64);   // head (lane&1)
            float v2 = a23 + __shfl_xor(g23, 1, 64);   // head 2+(lane&1)
            float keep = (lane & 2) ? v2 : u;
            float give = (lane & 2) ? u : v2;
            float v = keep + __shfl_xor(give, 2, 64);  // head (lane&3)
            v += __shfl_xor(v, 4, 64);
            v += __shfl_xor(v, 8, 64);
            v += __shfl_xor(v, 16, 64);
            v += __shfl_xor(v, 32, 64);
            unsigned char mk = (rr == 0) ? mb.x : (rr == 1) ? mb.y : (rr == 2) ? mb.z : mb.w;
            float p = __expf(mk ? -INFINITY : v);
            zacc += p;      // p is already the FULL row sum -> zacc is the
            ss[rr] = p;     // complete chunk-partial Z for head (lane&3).
            // broadcast (permuted): pj = p of head (lane&3)^j
            float p1 = __shfl_xor(p, 1, 64);
            float p2 = __shfl_xor(p, 2, 64);
            float p3 = __shfl_xor(p1, 2, 64);
#pragma unroll
            for (int kk = 0; kk < 4; kk++) {
                float4 kq = kv[cur][kk];
                acc[0][kk].x += p  * kq.x; acc[0][kk].y += p  * kq.y; acc[0][kk].z += p  * kq.z; acc[0][kk].w += p  * kq.w;
                acc[1][kk].x += p1 * kq.x; acc[1][kk].y += p1 * kq.y; acc[1][kk].z += p1 * kq.z; acc[1][kk].w += p1 * kq.w;
                acc[2][kk].x += p2 * kq.x; acc[2][kk].y += p2 * kq.y; acc[2][kk].z += p2 * kq.z; acc[2][kk].w += p2 * kq.w;
                acc[3][kk].x += p3 * kq.x; acc[3][kk].y += p3 * kq.y; acc[3][kk].z += p3 * kq.z; acc[3][kk].w += p3 * kq.w;
            }
        }
        if (lane < 4) {
            float4 o = make_float4(ss[0], ss[1], ss[2], ss[3]);
            *(float4*)&pout[((size_t)(hg * 4 + lane) * B + b) * L + l0 + rb * 4] = o;
        }
    }

    // phased LDS merge across chunks; un-permute head mapping h = hg*4+(hl^j)
    __syncthreads();
    for (int ph = 0; ph < 4; ph++) {
        if (chunk == ph) {
#pragma unroll
            for (int j = 0; j < 4; j++) {
                int h = hg * 4 + (hl ^ j);
                float* dst = &ctxl[(size_t)h * C + lane * 4];
                if (ph == 0) {
#pragma unroll
                    for (int kk = 0; kk < 4; kk++)
                        *(float4*)&dst[kk * 256] = acc[j][kk];
                } else {
#pragma unroll
                    for (int kk = 0; kk < 4; kk++) {
                        float4 o = *(const float4*)&dst[kk * 256];
                        float4 a = acc[j][kk];
                        o.x += a.x; o.y += a.y; o.z += a.z; o.w += a.w;
                        *(float4*)&dst[kk * 256] = o;
                    }
                }
            }
            if (lane < 4) {
                if (ph == 0) zl[hg * 4 + lane] = zacc;
                else         zl[hg * 4 + lane] += zacc;
            }
        }
        __syncthreads();
    }
    float* ap = accpart + ((size_t)b * 4 + lp) * (NH * C);
#pragma unroll
    for (int i = 0; i < 4; i++) {
        int idx = t * 16 + i * 4;
        *(float4*)&ap[idx] = *(const float4*)&ctxl[idx];
    }
    if (t < NH) zpart[((size_t)b * 4 + lp) * NH + t] = zl[t];
}

// ---------------------------------------------------------------------------
// k_epilogue: per b — (A) Z reduce over 4 lp, (B) ctx = sum_lp accpart * zi
// -> LDS, (C) out[b,j] = bv[j] + wv[j,:]·ctx[n(j),:], (D) scale pout by zi.
__global__ __launch_bounds__(1024) void k_epilogue(
    const float* __restrict__ accpart, const float* __restrict__ zpart,
    const float* __restrict__ wvw, const float* __restrict__ bv,
    float* __restrict__ pout, float* __restrict__ out) {
    const int b = blockIdx.x;
    const int t = threadIdx.x;
    __shared__ float ctxl[NH * C];
    __shared__ float zi[NH];
    if (t < NH) {
        float z = 0.f;
#pragma unroll
        for (int lp = 0; lp < 4; lp++) z += zpart[((size_t)b * 4 + lp) * NH + t];
        zi[t] = 1.0f / z;
    }
    __syncthreads();
    // (B) ctx reduce into LDS
#pragma unroll
    for (int i = 0; i < 2; i++) {
        int f4 = i * 1024 + t;               // 0..2047 float4 index into [NH*C]
        float4 s = make_float4(0.f, 0.f, 0.f, 0.f);
#pragma unroll
        for (int lp = 0; lp < 4; lp++) {
            float4 a = *(const float4*)&accpart[((size_t)b * 4 + lp) * (NH * C) + f4 * 4];
            s.x += a.x; s.y += a.y; s.z += a.z; s.w += a.w;
        }
        float sc = zi[f4 >> 8];
        s.x *= sc; s.y *= sc; s.z *= sc; s.w *= sc;
        *(float4*)&ctxl[f4 * 4] = s;
    }
    __syncthreads();
    // (C) output projection: wave per 64 j's
    {
        int wv_i = t >> 6, lane = t & 63;
        for (int jj = 0; jj < 64; jj++) {
            int j = wv_i * 64 + jj;
            int n = j >> 7;
            float s = 0.f;
#pragma unroll
            for (int kk = 0; kk < 4; kk++) {
                float4 W = *(const float4*)&wvw[(size_t)j * C + kk * 256 + lane * 4];
                float4 cv = *(const float4*)&ctxl[(size_t)n * C + kk * 256 + lane * 4];
                s += W.x * cv.x + W.y * cv.y + W.z * cv.z + W.w * cv.w;
            }
#pragma unroll
            for (int off = 32; off; off >>= 1) s += __shfl_xor(s, off, 64);
            if (lane == 0) out[(size_t)b * (NH * DK) + j] = s + bv[j];
        }
    }
    // (D) pout scale (rows (n,b), all l)
    float4* p4 = (float4*)pout;
#pragma unroll
    for (int i = 0; i < 4; i++) {
        int e = i * 1024 + t;                // 0..4095 = 8 rows x 512 float4
        int n = e >> 9, off = e & 511;
        size_t idx = ((size_t)n * B + b) * (L / 4) + off;
        float4 v = p4[idx];
        float sc = zi[n];
        v.x *= sc; v.y *= sc; v.z *= sc; v.w *= sc;
        p4[idx] = v;
    }
}

// ---------------------------------------------------------------------------
extern "C" void kernel_launch(void* const* d_in, const int* in_sizes, int n_in,
                              void* d_out, int out_size, void* d_ws, size_t ws_size,
                              hipStream_t stream) {
    const float* q    = (const float*)d_in[0];
    const float* kmat = (const float*)d_in[1];
    const unsigned char* mask = (const unsigned char*)d_in[2];
    const float* wq = (const float*)d_in[3];
    const float* bq = (const float*)d_in[4];
    const float* wk = (const float*)d_in[5];
    // d_in[6] = w_ks_b: softmax-invariant -> unused.
    const float* wv = (const float*)d_in[7];
    const float* bv = (const float*)d_in[8];

    float* out  = (float*)d_out;            // (64, 1024)
    float* attn = out + B * NH * DK;        // (8*64, 2048): exp(s) -> scaled

    float* ws      = (float*)d_ws;
    float* qs      = ws;                     // 65536 floats (dead after k_qtilde)
    float* zpart   = ws;                     // 2048 floats overlay (64*4*8)
    float* qtilde  = ws + 65536;             // 524288 floats
    float* accpart = ws + 65536 + 524288;    // 64*4*8*1024 = 2097152 floats

    hipLaunchKernelGGL(k_qs, dim3(256), dim3(256), 0, stream, q, wq, bq, qs);
    hipLaunchKernelGGL(k_qtilde, dim3(32, 8), dim3(256), 0, stream, qs, wk, qtilde);
    hipLaunchKernelGGL(k_fused3, dim3(64, 4), dim3(512), 0, stream,
                       kmat, qtilde, mask, attn, accpart, zpart);
    hipLaunchKernelGGL(k_epilogue, dim3(64), dim3(1024), 0, stream,
                       accpart, zpart, wv, bv, attn, out);
}

// Round 12
// 244.119 us; speedup vs baseline: 2.6881x; 1.1083x over previous
//
#include <hip/hip_runtime.h>
#include <hip/hip_bf16.h>
#include <math.h>

#define B 64
#define L 2048
#define C 1024          // D_K = D_Q
#define NH 8
#define DK 128
#define SCALE 0.08838834764831845f   // 1/sqrt(128)

// ---------------------------------------------------------------------------
// k_qs: qs[b, j] = bias[j] + sum_c q[b,c] * wq[j,c]   (64 x 1024)
__global__ void k_qs(const float* __restrict__ q, const float* __restrict__ wq,
                     const float* __restrict__ bq, float* __restrict__ qs) {
    int t = threadIdx.x, w = t >> 6, lane = t & 63;
    int j = blockIdx.x * 4 + w;
    float4 W[4];
#pragma unroll
    for (int kk = 0; kk < 4; kk++)
        W[kk] = *(const float4*)&wq[(size_t)j * C + kk * 256 + lane * 4];
    float bj = bq[j];
    for (int b = 0; b < B; b++) {
        float s = 0.f;
#pragma unroll
        for (int kk = 0; kk < 4; kk++) {
            float4 qv = *(const float4*)&q[(size_t)b * C + kk * 256 + lane * 4];
            s += W[kk].x * qv.x + W[kk].y * qv.y + W[kk].z * qv.z + W[kk].w * qv.w;
        }
#pragma unroll
        for (int off = 32; off; off >>= 1) s += __shfl_xor(s, off, 64);
        if (lane == 0) qs[(size_t)b * C + j] = s + bj;
    }
}

// ---------------------------------------------------------------------------
// k_qtilde: qtilde[b,n,c] = SCALE * sum_d qs[b, n*128+d] * wk[n*128+d, c]
// d-loop processes 4 rows/iter (independent loads -> 1/4 latency chain).
__global__ void k_qtilde(const float* __restrict__ qs, const float* __restrict__ wk,
                         float* __restrict__ qtilde) {
    int n = blockIdx.x >> 2, cc = blockIdx.x & 3, bg = blockIdx.y;
    int t = threadIdx.x;
    int c = cc * 256 + t;
    __shared__ float qss[8][128];
    for (int p = 0; p < 4; p++) {
        int e = p * 256 + t;
        int i = e >> 7, d = e & 127;
        qss[i][d] = qs[(size_t)(bg * 8 + i) * C + n * DK + d];
    }
    __syncthreads();
    float acc[8];
#pragma unroll
    for (int i = 0; i < 8; i++) acc[i] = 0.f;
    for (int d = 0; d < DK; d += 4) {
        float wv0 = wk[(size_t)(n * DK + d + 0) * C + c];
        float wv1 = wk[(size_t)(n * DK + d + 1) * C + c];
        float wv2 = wk[(size_t)(n * DK + d + 2) * C + c];
        float wv3 = wk[(size_t)(n * DK + d + 3) * C + c];
#pragma unroll
        for (int i = 0; i < 8; i++) {
            acc[i] += qss[i][d + 0] * wv0 + qss[i][d + 1] * wv1
                    + qss[i][d + 2] * wv2 + qss[i][d + 3] * wv3;
        }
    }
#pragma unroll
    for (int i = 0; i < 8; i++)
        qtilde[((size_t)(bg * 8 + i) * NH + n) * C + c] = acc[i] * SCALE;
}

// ---------------------------------------------------------------------------
// k_fused3 (round-5 verified, best-measured structure): one streaming pass
// over k. 512 thr = 8 waves = 4 chunks x 2 hg. Wave: 4 heads x 128 rows.
// Lane owns c-slots {kk*256+lane*4}. Direct exp (softmax shift-invariance;
// f32 safe) -> partials add plainly. Dist-1 register prefetch, no barriers
// in the main loop. launch_bounds(512,2): the only spill-free contract.
__global__ __launch_bounds__(512, 2) void k_fused3(
    const float* __restrict__ kmat, const float* __restrict__ qtilde,
    const unsigned char* __restrict__ mask,
    float* __restrict__ pout,             // (n*B + b)*L + l : exp(score)
    float* __restrict__ accpart,          // [b][lp4][n][C]
    float* __restrict__ zpart) {          // [b][lp4][n]
    const int b = blockIdx.x, lp = blockIdx.y;
    const int t = threadIdx.x, w = t >> 6, lane = t & 63;
    const int chunk = w >> 1;            // 0..3 (128 rows each)
    const int hg = w & 1;                // 0..1 (heads hg*4..hg*4+3)
    const int l0 = lp * 512 + chunk * 128;
    const int hl = lane & 3;

    __shared__ float ctxl[NH * C];       // 32 KB
    __shared__ float zl[NH];

    float4 qt[4][4];
#pragma unroll
    for (int j = 0; j < 4; j++)
#pragma unroll
        for (int kk = 0; kk < 4; kk++)
            qt[j][kk] = *(const float4*)&qtilde[((size_t)b * NH + hg * 4 + j) * C + kk * 256 + lane * 4];

    float4 acc[4][4];
#pragma unroll
    for (int j = 0; j < 4; j++)
#pragma unroll
        for (int kk = 0; kk < 4; kk++) acc[j][kk] = make_float4(0.f, 0.f, 0.f, 0.f);
    float zacc = 0.f;

    const float* kp = kmat + ((size_t)b * L + l0) * C + lane * 4;
    const unsigned char* mp = mask + (size_t)b * L + l0;

    float4 kv[2][4];
#pragma unroll
    for (int kk = 0; kk < 4; kk++) kv[0][kk] = *(const float4*)(kp + kk * 256);

    for (int rb = 0; rb < 32; rb++) {
        uchar4 mb = *(const uchar4*)&mp[rb * 4];
        float ss[4];
#pragma unroll
        for (int rr = 0; rr < 4; rr++) {
            const int r = rb * 4 + rr;
            const int cur = r & 1;
            if (r < 127) {
                const float* np = kp + (size_t)(r + 1) * C;
#pragma unroll
                for (int kk = 0; kk < 4; kk++)
                    kv[cur ^ 1][kk] = *(const float4*)(np + kk * 256);
            }
            float s0 = 0.f, s1 = 0.f, s2 = 0.f, s3 = 0.f;
#pragma unroll
            for (int kk = 0; kk < 4; kk++) {
                float4 kq = kv[cur][kk];
                s0 += qt[0][kk].x * kq.x + qt[0][kk].y * kq.y + qt[0][kk].z * kq.z + qt[0][kk].w * kq.w;
                s1 += qt[1][kk].x * kq.x + qt[1][kk].y * kq.y + qt[1][kk].z * kq.z + qt[1][kk].w * kq.w;
                s2 += qt[2][kk].x * kq.x + qt[2][kk].y * kq.y + qt[2][kk].z * kq.z + qt[2][kk].w * kq.w;
                s3 += qt[3][kk].x * kq.x + qt[3][kk].y * kq.y + qt[3][kk].z * kq.z + qt[3][kk].w * kq.w;
            }
            // butterfly: lane ends with full score of head (lane&3)
            float a01 = (lane & 1) ? s1 : s0;
            float g01 = (lane & 1) ? s0 : s1;
            float a23 = (lane & 1) ? s3 : s2;
            float g23 = (lane & 1) ? s2 : s3;
            float u  = a01 + __shfl_xor(g01, 1, 64);   // head (lane&1)
            float v2 = a23 + __shfl_xor(g23, 1, 64);   // head 2+(lane&1)
            float keep = (lane & 2) ? v2 : u;
            float give = (lane & 2) ? u : v2;
            float v = keep + __shfl_xor(give, 2, 64);  // head (lane&3)
            v += __shfl_xor(v, 4, 64);
            v += __shfl_xor(v, 8, 64);
            v += __shfl_xor(v, 16, 64);
            v += __shfl_xor(v, 32, 64);
            unsigned char mk = (rr == 0) ? mb.x : (rr == 1) ? mb.y : (rr == 2) ? mb.z : mb.w;
            float p = __expf(mk ? -INFINITY : v);
            zacc += p;      // p is already the FULL row sum -> zacc is the
            ss[rr] = p;     // complete chunk-partial Z for head (lane&3).
            // broadcast (permuted): pj = p of head (lane&3)^j
            float p1 = __shfl_xor(p, 1, 64);
            float p2 = __shfl_xor(p, 2, 64);
            float p3 = __shfl_xor(p1, 2, 64);
#pragma unroll
            for (int kk = 0; kk < 4; kk++) {
                float4 kq = kv[cur][kk];
                acc[0][kk].x += p  * kq.x; acc[0][kk].y += p  * kq.y; acc[0][kk].z += p  * kq.z; acc[0][kk].w += p  * kq.w;
                acc[1][kk].x += p1 * kq.x; acc[1][kk].y += p1 * kq.y; acc[1][kk].z += p1 * kq.z; acc[1][kk].w += p1 * kq.w;
                acc[2][kk].x += p2 * kq.x; acc[2][kk].y += p2 * kq.y; acc[2][kk].z += p2 * kq.z; acc[2][kk].w += p2 * kq.w;
                acc[3][kk].x += p3 * kq.x; acc[3][kk].y += p3 * kq.y; acc[3][kk].z += p3 * kq.z; acc[3][kk].w += p3 * kq.w;
            }
        }
        if (lane < 4) {
            float4 o = make_float4(ss[0], ss[1], ss[2], ss[3]);
            *(float4*)&pout[((size_t)(hg * 4 + lane) * B + b) * L + l0 + rb * 4] = o;
        }
    }

    // phased LDS merge across chunks; un-permute head mapping h = hg*4+(hl^j)
    __syncthreads();
    for (int ph = 0; ph < 4; ph++) {
        if (chunk == ph) {
#pragma unroll
            for (int j = 0; j < 4; j++) {
                int h = hg * 4 + (hl ^ j);
                float* dst = &ctxl[(size_t)h * C + lane * 4];
                if (ph == 0) {
#pragma unroll
                    for (int kk = 0; kk < 4; kk++)
                        *(float4*)&dst[kk * 256] = acc[j][kk];
                } else {
#pragma unroll
                    for (int kk = 0; kk < 4; kk++) {
                        float4 o = *(const float4*)&dst[kk * 256];
                        float4 a = acc[j][kk];
                        o.x += a.x; o.y += a.y; o.z += a.z; o.w += a.w;
                        *(float4*)&dst[kk * 256] = o;
                    }
                }
            }
            if (lane < 4) {
                if (ph == 0) zl[hg * 4 + lane] = zacc;
                else         zl[hg * 4 + lane] += zacc;
            }
        }
        __syncthreads();
    }
    float* ap = accpart + ((size_t)b * 4 + lp) * (NH * C);
#pragma unroll
    for (int i = 0; i < 4; i++) {
        int idx = t * 16 + i * 4;
        *(float4*)&ap[idx] = *(const float4*)&ctxl[idx];
    }
    if (t < NH) zpart[((size_t)b * 4 + lp) * NH + t] = zl[t];
}

// ---------------------------------------------------------------------------
// k_combine2 (round-6 verified): ctx[b,n,c] = (sum_lp accpart) / Z; ALSO
// scales pout by Zinv (fused attn normalize). grid (64 b, 4 cq), 256 thr.
__global__ void k_combine2(const float* __restrict__ accpart, const float* __restrict__ zpart,
                           float* __restrict__ ctx, float* __restrict__ pout) {
    int b = blockIdx.x, cq = blockIdx.y;
    int t = threadIdx.x;
    int c = cq * 256 + t;
    __shared__ float zi[NH];
    if (t < NH) {
        float z = 0.f;
#pragma unroll
        for (int lpp = 0; lpp < 4; lpp++) z += zpart[((size_t)b * 4 + lpp) * NH + t];
        zi[t] = 1.0f / z;
    }
    __syncthreads();
#pragma unroll
    for (int n = 0; n < NH; n++) {
        float s = 0.f;
#pragma unroll
        for (int lpp = 0; lpp < 4; lpp++)
            s += accpart[(((size_t)b * 4 + lpp) * NH + n) * C + c];
        ctx[((size_t)b * NH + n) * C + c] = s * zi[n];
    }
    // attn normalize: rows (n, b), l-range [cq*512, cq*512+512)
#pragma unroll
    for (int n = 0; n < NH; n++) {
        float zin = zi[n];
        float2* pp = (float2*)&pout[((size_t)n * B + b) * L + cq * 512];
        float2 v = pp[t];
        v.x *= zin; v.y *= zin;
        pp[t] = v;
    }
}

// ---------------------------------------------------------------------------
// k_out (round-5 verified): output[b, j] = bv[j] + sum_c wv[j,c]*ctx[b,n(j),c]
__global__ void k_out(const float* __restrict__ ctx, const float* __restrict__ wv,
                      const float* __restrict__ bv, float* __restrict__ out) {
    int t = threadIdx.x, w = t >> 6, lane = t & 63;
    int j = blockIdx.x * 4 + w;
    int n = j >> 7;
    float4 W[4];
#pragma unroll
    for (int kk = 0; kk < 4; kk++)
        W[kk] = *(const float4*)&wv[(size_t)j * C + kk * 256 + lane * 4];
    float bj = bv[j];
    for (int b = 0; b < B; b++) {
        float s = 0.f;
#pragma unroll
        for (int kk = 0; kk < 4; kk++) {
            float4 cv = *(const float4*)&ctx[((size_t)b * NH + n) * C + kk * 256 + lane * 4];
            s += W[kk].x * cv.x + W[kk].y * cv.y + W[kk].z * cv.z + W[kk].w * cv.w;
        }
#pragma unroll
        for (int off = 32; off; off >>= 1) s += __shfl_xor(s, off, 64);
        if (lane == 0) out[(size_t)b * (NH * DK) + j] = s + bj;
    }
}

// ---------------------------------------------------------------------------
extern "C" void kernel_launch(void* const* d_in, const int* in_sizes, int n_in,
                              void* d_out, int out_size, void* d_ws, size_t ws_size,
                              hipStream_t stream) {
    const float* q    = (const float*)d_in[0];
    const float* kmat = (const float*)d_in[1];
    const unsigned char* mask = (const unsigned char*)d_in[2];
    const float* wq = (const float*)d_in[3];
    const float* bq = (const float*)d_in[4];
    const float* wk = (const float*)d_in[5];
    // d_in[6] = w_ks_b: softmax-invariant -> unused.
    const float* wv = (const float*)d_in[7];
    const float* bv = (const float*)d_in[8];

    float* out  = (float*)d_out;            // (64, 1024)
    float* attn = out + B * NH * DK;        // (8*64, 2048): exp(s) -> scaled

    float* ws      = (float*)d_ws;
    float* qs      = ws;                     // 65536 floats (dead after k_qtilde)
    float* zpart   = ws;                     // 2048 floats overlay (64*4*8)
    float* qtilde  = ws + 65536;             // 524288 floats, reused as ctx
    float* ctx     = qtilde;
    float* accpart = ws + 65536 + 524288;    // 2097152 floats

    hipLaunchKernelGGL(k_qs, dim3(256), dim3(256), 0, stream, q, wq, bq, qs);
    hipLaunchKernelGGL(k_qtilde, dim3(32, 8), dim3(256), 0, stream, qs, wk, qtilde);
    hipLaunchKernelGGL(k_fused3, dim3(64, 4), dim3(512), 0, stream,
                       kmat, qtilde, mask, attn, accpart, zpart);
    hipLaunchKernelGGL(k_combine2, dim3(64, 4), dim3(256), 0, stream,
                       accpart, zpart, ctx, attn);
    hipLaunchKernelGGL(k_out, dim3(256), dim3(256), 0, stream, ctx, wv, bv, out);
}

// Round 13
// 221.699 us; speedup vs baseline: 2.9599x; 1.1011x over previous
//
#include <hip/hip_runtime.h>
#include <hip/hip_bf16.h>
#include <math.h>

#define B 64
#define L 2048
#define C 1024          // D_K = D_Q
#define NH 8
#define DK 128
#define SCALE 0.08838834764831845f   // 1/sqrt(128)

// DPP helper: dst = dpp_perm(src) per CTRL; masked-off/invalid lanes yield 0.
// (update_dpp(old=0, ..., bound_ctrl=true) -> adding the result is safe.)
template<int CTRL, int RMASK = 0xF>
__device__ __forceinline__ float dppmov(float x) {
    return __int_as_float(__builtin_amdgcn_update_dpp(
        0, __float_as_int(x), CTRL, RMASK, 0xF, true));
}
// Full wave64 sum via DPP (AMD cross-lane blog pattern); result in LANE 63.
__device__ __forceinline__ float wave_sum_dpp(float s) {
    s += dppmov<0x111>(s);          // row_shr:1
    s += dppmov<0x112>(s);          // row_shr:2
    s += dppmov<0x114>(s);          // row_shr:4
    s += dppmov<0x118>(s);          // row_shr:8  -> lane 15/31/47/63 = row sums
    s += dppmov<0x142, 0xa>(s);     // row_bcast:15 into rows 1,3
    s += dppmov<0x143, 0xc>(s);     // row_bcast:31 into rows 2,3 -> lane63 total
    return s;
}

// ---------------------------------------------------------------------------
// k_qs: qs[b, j] = bias[j] + sum_c q[b,c] * wq[j,c]   (64 x 1024)
__global__ void k_qs(const float* __restrict__ q, const float* __restrict__ wq,
                     const float* __restrict__ bq, float* __restrict__ qs) {
    int t = threadIdx.x, w = t >> 6, lane = t & 63;
    int j = blockIdx.x * 4 + w;
    float4 W[4];
#pragma unroll
    for (int kk = 0; kk < 4; kk++)
        W[kk] = *(const float4*)&wq[(size_t)j * C + kk * 256 + lane * 4];
    float bj = bq[j];
    for (int b = 0; b < B; b++) {
        float s = 0.f;
#pragma unroll
        for (int kk = 0; kk < 4; kk++) {
            float4 qv = *(const float4*)&q[(size_t)b * C + kk * 256 + lane * 4];
            s += W[kk].x * qv.x + W[kk].y * qv.y + W[kk].z * qv.z + W[kk].w * qv.w;
        }
        s = wave_sum_dpp(s);
        if (lane == 63) qs[(size_t)b * C + j] = s + bj;
    }
}

// ---------------------------------------------------------------------------
// k_qtilde: qtilde[b,n,c] = SCALE * sum_d qs[b, n*128+d] * wk[n*128+d, c]
__global__ void k_qtilde(const float* __restrict__ qs, const float* __restrict__ wk,
                         float* __restrict__ qtilde) {
    int n = blockIdx.x >> 2, cc = blockIdx.x & 3, bg = blockIdx.y;
    int t = threadIdx.x;
    int c = cc * 256 + t;
    __shared__ float qss[8][128];
    for (int p = 0; p < 4; p++) {
        int e = p * 256 + t;
        int i = e >> 7, d = e & 127;
        qss[i][d] = qs[(size_t)(bg * 8 + i) * C + n * DK + d];
    }
    __syncthreads();
    float acc[8];
#pragma unroll
    for (int i = 0; i < 8; i++) acc[i] = 0.f;
    for (int d = 0; d < DK; d += 4) {
        float wv0 = wk[(size_t)(n * DK + d + 0) * C + c];
        float wv1 = wk[(size_t)(n * DK + d + 1) * C + c];
        float wv2 = wk[(size_t)(n * DK + d + 2) * C + c];
        float wv3 = wk[(size_t)(n * DK + d + 3) * C + c];
#pragma unroll
        for (int i = 0; i < 8; i++) {
            acc[i] += qss[i][d + 0] * wv0 + qss[i][d + 1] * wv1
                    + qss[i][d + 2] * wv2 + qss[i][d + 3] * wv3;
        }
    }
#pragma unroll
    for (int i = 0; i < 8; i++)
        qtilde[((size_t)(bg * 8 + i) * NH + n) * C + c] = acc[i] * SCALE;
}

// ---------------------------------------------------------------------------
// k_fused8: round-5 fused3 structure with the 9 LDS-shuffles/row replaced by
// DPP (VALU-rate) + 2 LDS ops. 512 thr = 8 waves = 4 chunks x 2 hg; wave:
// 4 heads x 128 rows; lane owns c-slots {kk*256+lane*4}. Direct exp ->
// partials add plainly. Dist-1 reg prefetch, no main-loop barriers, (512,2).
__global__ __launch_bounds__(512, 2) void k_fused8(
    const float* __restrict__ kmat, const float* __restrict__ qtilde,
    const unsigned char* __restrict__ mask,
    float* __restrict__ pout,             // (n*B + b)*L + l : exp(score)
    float* __restrict__ accpart,          // [b][lp4][n][C]
    float* __restrict__ zpart) {          // [b][lp4][n]
    const int b = blockIdx.x, lp = blockIdx.y;
    const int t = threadIdx.x, w = t >> 6, lane = t & 63;
    const int chunk = w >> 1;            // 0..3 (128 rows each)
    const int hg = w & 1;                // 0..1 (heads hg*4..hg*4+3)
    const int l0 = lp * 512 + chunk * 128;
    const int hl = lane & 3;

    __shared__ float ctxl[NH * C];       // 32 KB
    __shared__ float zl[NH];

    float4 qt[4][4];
#pragma unroll
    for (int j = 0; j < 4; j++)
#pragma unroll
        for (int kk = 0; kk < 4; kk++)
            qt[j][kk] = *(const float4*)&qtilde[((size_t)b * NH + hg * 4 + j) * C + kk * 256 + lane * 4];

    float4 acc[4][4];
#pragma unroll
    for (int j = 0; j < 4; j++)
#pragma unroll
        for (int kk = 0; kk < 4; kk++) acc[j][kk] = make_float4(0.f, 0.f, 0.f, 0.f);
    float zacc = 0.f;

    const float* kp = kmat + ((size_t)b * L + l0) * C + lane * 4;
    const unsigned char* mp = mask + (size_t)b * L + l0;

    float4 kv[2][4];
#pragma unroll
    for (int kk = 0; kk < 4; kk++) kv[0][kk] = *(const float4*)(kp + kk * 256);

    for (int rb = 0; rb < 32; rb++) {
        uchar4 mb = *(const uchar4*)&mp[rb * 4];
        float ss[4];
#pragma unroll
        for (int rr = 0; rr < 4; rr++) {
            const int r = rb * 4 + rr;
            const int cur = r & 1;
            if (r < 127) {
                const float* np = kp + (size_t)(r + 1) * C;
#pragma unroll
                for (int kk = 0; kk < 4; kk++)
                    kv[cur ^ 1][kk] = *(const float4*)(np + kk * 256);
            }
            float s0 = 0.f, s1 = 0.f, s2 = 0.f, s3 = 0.f;
#pragma unroll
            for (int kk = 0; kk < 4; kk++) {
                float4 kq = kv[cur][kk];
                s0 += qt[0][kk].x * kq.x + qt[0][kk].y * kq.y + qt[0][kk].z * kq.z + qt[0][kk].w * kq.w;
                s1 += qt[1][kk].x * kq.x + qt[1][kk].y * kq.y + qt[1][kk].z * kq.z + qt[1][kk].w * kq.w;
                s2 += qt[2][kk].x * kq.x + qt[2][kk].y * kq.y + qt[2][kk].z * kq.z + qt[2][kk].w * kq.w;
                s3 += qt[3][kk].x * kq.x + qt[3][kk].y * kq.y + qt[3][kk].z * kq.z + qt[3][kk].w * kq.w;
            }
            // butterfly, DPP edition: lane ends with full score of head (lane&3)
            float a01 = (lane & 1) ? s1 : s0;
            float g01 = (lane & 1) ? s0 : s1;
            float a23 = (lane & 1) ? s3 : s2;
            float g23 = (lane & 1) ? s2 : s3;
            float u  = a01 + dppmov<0xB1>(g01);        // quad_perm xor1
            float v2 = a23 + dppmov<0xB1>(g23);
            float keep = (lane & 2) ? v2 : u;
            float give = (lane & 2) ? u : v2;
            float v = keep + dppmov<0x4E>(give);       // quad_perm xor2
            v += dppmov<0x124>(v);                     // row_ror:4
            v += dppmov<0x128>(v);                     // row_ror:8
            // now v = class-sum within each 16-lane row; combine 4 rows:
            v += __int_as_float(__builtin_amdgcn_ds_swizzle(
                     __float_as_int(v), 0x401F));      // xor16 (within 32-half)
            v += __shfl_xor(v, 32, 64);                // cross-32
            unsigned char mk = (rr == 0) ? mb.x : (rr == 1) ? mb.y : (rr == 2) ? mb.z : mb.w;
            float p = __expf(mk ? -INFINITY : v);
            zacc += p;      // p is already the FULL row sum -> zacc is the
            ss[rr] = p;     // complete chunk-partial Z for head (lane&3).
            // broadcast (permuted) via quad_perm: pj = p of head (lane&3)^j
            float p1 = dppmov<0xB1>(p);
            float p2 = dppmov<0x4E>(p);
            float p3 = dppmov<0x4E>(p1);
#pragma unroll
            for (int kk = 0; kk < 4; kk++) {
                float4 kq = kv[cur][kk];
                acc[0][kk].x += p  * kq.x; acc[0][kk].y += p  * kq.y; acc[0][kk].z += p  * kq.z; acc[0][kk].w += p  * kq.w;
                acc[1][kk].x += p1 * kq.x; acc[1][kk].y += p1 * kq.y; acc[1][kk].z += p1 * kq.z; acc[1][kk].w += p1 * kq.w;
                acc[2][kk].x += p2 * kq.x; acc[2][kk].y += p2 * kq.y; acc[2][kk].z += p2 * kq.z; acc[2][kk].w += p2 * kq.w;
                acc[3][kk].x += p3 * kq.x; acc[3][kk].y += p3 * kq.y; acc[3][kk].z += p3 * kq.z; acc[3][kk].w += p3 * kq.w;
            }
        }
        if (lane < 4) {
            float4 o = make_float4(ss[0], ss[1], ss[2], ss[3]);
            *(float4*)&pout[((size_t)(hg * 4 + lane) * B + b) * L + l0 + rb * 4] = o;
        }
    }

    // phased LDS merge across chunks; un-permute head mapping h = hg*4+(hl^j)
    __syncthreads();
    for (int ph = 0; ph < 4; ph++) {
        if (chunk == ph) {
#pragma unroll
            for (int j = 0; j < 4; j++) {
                int h = hg * 4 + (hl ^ j);
                float* dst = &ctxl[(size_t)h * C + lane * 4];
                if (ph == 0) {
#pragma unroll
                    for (int kk = 0; kk < 4; kk++)
                        *(float4*)&dst[kk * 256] = acc[j][kk];
                } else {
#pragma unroll
                    for (int kk = 0; kk < 4; kk++) {
                        float4 o = *(const float4*)&dst[kk * 256];
                        float4 a = acc[j][kk];
                        o.x += a.x; o.y += a.y; o.z += a.z; o.w += a.w;
                        *(float4*)&dst[kk * 256] = o;
                    }
                }
            }
            if (lane < 4) {
                if (ph == 0) zl[hg * 4 + lane] = zacc;
                else         zl[hg * 4 + lane] += zacc;
            }
        }
        __syncthreads();
    }
    float* ap = accpart + ((size_t)b * 4 + lp) * (NH * C);
#pragma unroll
    for (int i = 0; i < 4; i++) {
        int idx = t * 16 + i * 4;
        *(float4*)&ap[idx] = *(const float4*)&ctxl[idx];
    }
    if (t < NH) zpart[((size_t)b * 4 + lp) * NH + t] = zl[t];
}

// ---------------------------------------------------------------------------
// k_combine2: ctx[b,n,c] = (sum_lp accpart) / Z; ALSO scales pout by Zinv
// (fused attn normalize). grid (64 b, 4 cq), 256 thr.
__global__ void k_combine2(const float* __restrict__ accpart, const float* __restrict__ zpart,
                           float* __restrict__ ctx, float* __restrict__ pout) {
    int b = blockIdx.x, cq = blockIdx.y;
    int t = threadIdx.x;
    int c = cq * 256 + t;
    __shared__ float zi[NH];
    if (t < NH) {
        float z = 0.f;
#pragma unroll
        for (int lpp = 0; lpp < 4; lpp++) z += zpart[((size_t)b * 4 + lpp) * NH + t];
        zi[t] = 1.0f / z;
    }
    __syncthreads();
#pragma unroll
    for (int n = 0; n < NH; n++) {
        float s = 0.f;
#pragma unroll
        for (int lpp = 0; lpp < 4; lpp++)
            s += accpart[(((size_t)b * 4 + lpp) * NH + n) * C + c];
        ctx[((size_t)b * NH + n) * C + c] = s * zi[n];
    }
    // attn normalize: rows (n, b), l-range [cq*512, cq*512+512)
#pragma unroll
    for (int n = 0; n < NH; n++) {
        float zin = zi[n];
        float2* pp = (float2*)&pout[((size_t)n * B + b) * L + cq * 512];
        float2 v = pp[t];
        v.x *= zin; v.y *= zin;
        pp[t] = v;
    }
}

// ---------------------------------------------------------------------------
// k_out: output[b, j] = bv[j] + sum_c wv[j,c] * ctx[b, n(j), c]
__global__ void k_out(const float* __restrict__ ctx, const float* __restrict__ wv,
                      const float* __restrict__ bv, float* __restrict__ out) {
    int t = threadIdx.x, w = t >> 6, lane = t & 63;
    int j = blockIdx.x * 4 + w;
    int n = j >> 7;
    float4 W[4];
#pragma unroll
    for (int kk = 0; kk < 4; kk++)
        W[kk] = *(const float4*)&wv[(size_t)j * C + kk * 256 + lane * 4];
    float bj = bv[j];
    for (int b = 0; b < B; b++) {
        float s = 0.f;
#pragma unroll
        for (int kk = 0; kk < 4; kk++) {
            float4 cv = *(const float4*)&ctx[((size_t)b * NH + n) * C + kk * 256 + lane * 4];
            s += W[kk].x * cv.x + W[kk].y * cv.y + W[kk].z * cv.z + W[kk].w * cv.w;
        }
        s = wave_sum_dpp(s);
        if (lane == 63) out[(size_t)b * (NH * DK) + j] = s + bj;
    }
}

// ---------------------------------------------------------------------------
extern "C" void kernel_launch(void* const* d_in, const int* in_sizes, int n_in,
                              void* d_out, int out_size, void* d_ws, size_t ws_size,
                              hipStream_t stream) {
    const float* q    = (const float*)d_in[0];
    const float* kmat = (const float*)d_in[1];
    const unsigned char* mask = (const unsigned char*)d_in[2];
    const float* wq = (const float*)d_in[3];
    const float* bq = (const float*)d_in[4];
    const float* wk = (const float*)d_in[5];
    // d_in[6] = w_ks_b: softmax-invariant -> unused.
    const float* wv = (const float*)d_in[7];
    const float* bv = (const float*)d_in[8];

    float* out  = (float*)d_out;            // (64, 1024)
    float* attn = out + B * NH * DK;        // (8*64, 2048): exp(s) -> scaled

    float* ws      = (float*)d_ws;
    float* qs      = ws;                     // 65536 floats (dead after k_qtilde)
    float* zpart   = ws;                     // 2048 floats overlay (64*4*8)
    float* qtilde  = ws + 65536;             // 524288 floats, reused as ctx
    float* ctx     = qtilde;
    float* accpart = ws + 65536 + 524288;    // 2097152 floats

    hipLaunchKernelGGL(k_qs, dim3(256), dim3(256), 0, stream, q, wq, bq, qs);
    hipLaunchKernelGGL(k_qtilde, dim3(32, 8), dim3(256), 0, stream, qs, wk, qtilde);
    hipLaunchKernelGGL(k_fused8, dim3(64, 4), dim3(512), 0, stream,
                       kmat, qtilde, mask, attn, accpart, zpart);
    hipLaunchKernelGGL(k_combine2, dim3(64, 4), dim3(256), 0, stream,
                       accpart, zpart, ctx, attn);
    hipLaunchKernelGGL(k_out, dim3(256), dim3(256), 0, stream, ctx, wv, bv, out);
}